// Round 6
// baseline (117.096 us; speedup 1.0000x reference)
//
#include <hip/hip_runtime.h>

// MonarchEmbedding: out[t, kr*32+o] = (kr&1)==(k>>5) ? L[k,b1,kr>>1] * R[kr,k&31,o] : 0
// where v = x[t], k = v/786, and L[k,b1,kr>>1] = Lflat[v*16 + (kr>>1)].
// Derivation: p[c]=(c%64)*16+c//64 (perfect_shuffle(64,1024)); BLd[v,col] nonzero
// iff col//16==k, so the einsum over b collapses to a single product. Exact fp32
// match to the reference (the other terms are exact zeros).
//
// R6: TIMING PROBE. Kernel body is identical to R4 (best: 84.0 us). We launch
// it 4x (idempotent) to measure the kernel's true duration via the dur_us
// aggregate with 4x leverage, since rocprof top-5 only shows harness fills:
//   dur_us ~155-165  => kernel ~26 us, headroom exists -> restructure next
//   dur_us ~115-122  => kernel ~12 us, at store roofline -> revert & stop

#define BL1 786
#define TOK_PER_BLOCK 8
#define PROBE_LAUNCHES 4

typedef float vfloat4 __attribute__((ext_vector_type(4)));

__global__ __launch_bounds__(256) void monarch_embed_kernel(
    const int* __restrict__ x,
    const float* __restrict__ L,     // [64, 786, 16] flat
    const float* __restrict__ R,     // [32, 32, 32]  flat
    vfloat4* __restrict__ out)       // [n_tok, 256] float4
{
    const int t  = threadIdx.x;        // 0..255
    const int kr = t >> 3;             // output row, 0..31
    const int o0 = (t & 7) << 2;       // col within row, multiple of 4
    const int base = blockIdx.x * TOK_PER_BLOCK;

    int v[TOK_PER_BLOCK];
#pragma unroll
    for (int i = 0; i < TOK_PER_BLOCK; ++i) v[i] = x[base + i];

#pragma unroll
    for (int i = 0; i < TOK_PER_BLOCK; ++i) {
        const int k = v[i] / BL1;      // magic-mul

        vfloat4 val = (vfloat4)(0.f);
        if ((kr & 1) == (k >> 5)) {
            const float   l = L[v[i] * 16 + (kr >> 1)];
            const vfloat4 r = *reinterpret_cast<const vfloat4*>(
                R + ((kr << 5) + (k & 31)) * 32 + o0);
            val = l * r;
        }
        out[(size_t)(base + i) * 256 + t] = val;
    }
}

extern "C" void kernel_launch(void* const* d_in, const int* in_sizes, int n_in,
                              void* d_out, int out_size, void* d_ws, size_t ws_size,
                              hipStream_t stream) {
    const int*   x = (const int*)d_in[0];
    const float* L = (const float*)d_in[1];
    const float* R = (const float*)d_in[2];
    // d_in[3] = p, unused: closed form derived above for perfect_shuffle(64,1024).

    const int n_tok  = in_sizes[0];              // 8*2048 = 16384
    const int blocks = n_tok / TOK_PER_BLOCK;    // 2048
    for (int rep = 0; rep < PROBE_LAUNCHES; ++rep) {
        monarch_embed_kernel<<<dim3(blocks), dim3(256), 0, stream>>>(
            x, L, R, (vfloat4*)d_out);
    }
}

// Round 7
// 82.191 us; speedup vs baseline: 1.4247x; 1.4247x over previous
//
#include <hip/hip_runtime.h>

// MonarchEmbedding: out[t, kr*32+o] = (kr&1)==(k>>5) ? L[k,b1,kr>>1] * R[kr,k&31,o] : 0
// where v = x[t], k = v/786, and L[k,b1,kr>>1] = Lflat[v*16 + (kr>>1)].
// Derivation: p[c]=(c%64)*16+c//64 (perfect_shuffle(64,1024)); BLd[v,col] nonzero
// iff col//16==k, so the einsum over b collapses to a single product. Exact fp32
// match to the reference (the other terms are exact zeros).
//
// FINAL (R7 = R4 reverted from the R6 4x-probe): single launch.
// R6 probe measured the kernel at ~11.0 us = 6.1 TB/s store BW, matching the
// harness fill kernels (5.9-6.2 TB/s) = the machine's demonstrated HBM write
// ceiling. 64 MiB fp32 output must be written once; floor ~10.8 us. At roofline.

#define BL1 786
#define TOK_PER_BLOCK 8

typedef float vfloat4 __attribute__((ext_vector_type(4)));

__global__ __launch_bounds__(256) void monarch_embed_kernel(
    const int* __restrict__ x,
    const float* __restrict__ L,     // [64, 786, 16] flat
    const float* __restrict__ R,     // [32, 32, 32]  flat
    vfloat4* __restrict__ out)       // [n_tok, 256] float4
{
    const int t  = threadIdx.x;        // 0..255
    const int kr = t >> 3;             // output row, 0..31
    const int o0 = (t & 7) << 2;       // col within row, multiple of 4
    const int base = blockIdx.x * TOK_PER_BLOCK;

    int v[TOK_PER_BLOCK];
#pragma unroll
    for (int i = 0; i < TOK_PER_BLOCK; ++i) v[i] = x[base + i];

#pragma unroll
    for (int i = 0; i < TOK_PER_BLOCK; ++i) {
        const int k = v[i] / BL1;      // magic-mul

        vfloat4 val = (vfloat4)(0.f);
        if ((kr & 1) == (k >> 5)) {
            const float   l = L[v[i] * 16 + (kr >> 1)];
            const vfloat4 r = *reinterpret_cast<const vfloat4*>(
                R + ((kr << 5) + (k & 31)) * 32 + o0);
            val = l * r;
        }
        out[(size_t)(base + i) * 256 + t] = val;
    }
}

extern "C" void kernel_launch(void* const* d_in, const int* in_sizes, int n_in,
                              void* d_out, int out_size, void* d_ws, size_t ws_size,
                              hipStream_t stream) {
    const int*   x = (const int*)d_in[0];
    const float* L = (const float*)d_in[1];
    const float* R = (const float*)d_in[2];
    // d_in[3] = p, unused: closed form derived above for perfect_shuffle(64,1024).

    const int n_tok  = in_sizes[0];              // 8*2048 = 16384
    const int blocks = n_tok / TOK_PER_BLOCK;    // 2048
    monarch_embed_kernel<<<dim3(blocks), dim3(256), 0, stream>>>(
        x, L, R, (vfloat4*)d_out);
}